// Round 8
// baseline (217.763 us; speedup 1.0000x reference)
//
#include <hip/hip_runtime.h>
#include <hip/hip_bf16.h>
#include <stdint.h>

#define B_  2
#define S_  2048
#define D_  1024
#define H_  16
#define DH_ 64

typedef __attribute__((ext_vector_type(8))) __bf16    bf16x8;
typedef __attribute__((ext_vector_type(8))) _Float16  f16x8;
typedef __attribute__((ext_vector_type(2))) __fp16    fp16x2;   // cvt_pkrtz return type
typedef __attribute__((ext_vector_type(4))) float     f32x4;

__device__ inline unsigned short f2bf(float f) {
    union { float f; uint32_t u; } v; v.f = f;
    uint32_t r = (v.u + 0x7fffu + ((v.u >> 16) & 1u)) >> 16;
    return (unsigned short)r;
}

// async global->LDS, 16B per lane. LDS dest = wave-uniform base + lane*16.
__device__ __forceinline__ void g2l16(const unsigned short* g, unsigned short* l) {
    __builtin_amdgcn_global_load_lds(
        (const __attribute__((address_space(1))) unsigned int*)g,
        (__attribute__((address_space(3))) unsigned int*)l,
        16, 0, 0);
}

// ---------------- conversion kernels ----------------

__global__ void convert_x(const float* __restrict__ x, unsigned short* __restrict__ xb, int n) {
    int i = (blockIdx.x * blockDim.x + threadIdx.x) * 4;
    if (i < n) {
        float4 v = *(const float4*)(x + i);
        ushort4 o;
        o.x = f2bf(v.x); o.y = f2bf(v.y); o.z = f2bf(v.z); o.w = f2bf(v.w);
        *(ushort4*)(xb + i) = o;
    }
}

// transpose+convert 1024x1024 fp32 [K][N] -> bf16 [N][K]; z selects matrix
__global__ void transpose_w(const float* __restrict__ s0, const float* __restrict__ s1,
                            const float* __restrict__ s2, const float* __restrict__ s3,
                            unsigned short* __restrict__ d0, unsigned short* __restrict__ d1,
                            unsigned short* __restrict__ d2, unsigned short* __restrict__ d3) {
    __shared__ float tile[32][33];
    const float* src; unsigned short* dst;
    switch (blockIdx.z) {
        case 0: src = s0; dst = d0; break;
        case 1: src = s1; dst = d1; break;
        case 2: src = s2; dst = d2; break;
        default: src = s3; dst = d3; break;
    }
    int n0 = blockIdx.x * 32, k0 = blockIdx.y * 32;
    int tx = threadIdx.x, ty = threadIdx.y;   // (32, 8)
    for (int j = 0; j < 32; j += 8)
        tile[ty + j][tx] = src[(long)(k0 + ty + j) * 1024 + n0 + tx];
    __syncthreads();
    for (int j = 0; j < 32; j += 8)
        dst[(long)(n0 + ty + j) * 1024 + k0 + tx] = f2bf(tile[tx][ty + j]);
}

// ---------------- 128x128 MFMA GEMM, global_load_lds staging ----------------
// MODE 0: scatter epilogue -> Q[B,H,S,64] bf16 (PRE-SCALED by 0.125*log2e),
//         K[B,H,S,64] bf16, Vt[B,H,64,S] FP16
// MODE 1: C fp32 [M,1024] row-major
template<int MODE>
__global__ __launch_bounds__(256, 2)
void gemm128(const unsigned short* __restrict__ A, const unsigned short* __restrict__ Bt,
             unsigned short* __restrict__ Qo, unsigned short* __restrict__ Ko,
             unsigned short* __restrict__ Vt, float* __restrict__ Cout)
{
    __shared__ __align__(16) unsigned short As[128 * 64];
    __shared__ __align__(16) unsigned short Bs[128 * 64];
    const int tid  = threadIdx.x;
    const int lane = tid & 63, wid = tid >> 6;
    const int quad = lane >> 4, l15 = lane & 15;
    const int wm = wid >> 1, wn = wid & 1;
    const int bm = blockIdx.y, bn = blockIdx.x;
    const int K = 1024;
    f32x4 acc[4][4] = {};
    const long Abase = (long)bm * 128 * K;
    const long Bbase = (long)bn * 128 * K;

    for (int k0 = 0; k0 < K; k0 += 64) {
        __syncthreads();
#pragma unroll
        for (int i = 0; i < 4; i++) {
            int slot = i * 256 + wid * 64 + lane;
            int row = slot >> 3, cp = slot & 7;
            int c = cp ^ (row & 7);
            g2l16(A + Abase + (long)row * K + k0 + c * 8, &As[(i * 256 + wid * 64) * 8]);
        }
#pragma unroll
        for (int i = 0; i < 4; i++) {
            int slot = i * 256 + wid * 64 + lane;
            int row = slot >> 3, cp = slot & 7;
            int c = cp ^ (row & 7);
            g2l16(Bt + Bbase + (long)row * K + k0 + c * 8, &Bs[(i * 256 + wid * 64) * 8]);
        }
        __syncthreads();
#pragma unroll
        for (int ks = 0; ks < 2; ks++) {
            bf16x8 af[4], bfr[4];
#pragma unroll
            for (int t = 0; t < 4; t++) {
                int ra = wm * 64 + t * 16 + l15;
                af[t]  = *(const bf16x8*)(As + ra * 64 + (((ks * 4 + quad) ^ (l15 & 7))) * 8);
                int rb = wn * 64 + t * 16 + l15;
                bfr[t] = *(const bf16x8*)(Bs + rb * 64 + (((ks * 4 + quad) ^ (l15 & 7))) * 8);
            }
#pragma unroll
            for (int tm = 0; tm < 4; tm++)
#pragma unroll
                for (int tn = 0; tn < 4; tn++)
                    acc[tm][tn] = __builtin_amdgcn_mfma_f32_16x16x32_bf16(af[tm], bfr[tn], acc[tm][tn], 0, 0, 0);
        }
    }

    const float Cq = 0.125f * 1.44269504f;   // score scale * log2(e), folded into Q
    for (int tm = 0; tm < 4; tm++)
        for (int tn = 0; tn < 4; tn++)
            for (int r = 0; r < 4; r++) {
                int gm = bm * 128 + wm * 64 + tm * 16 + quad * 4 + r;
                int gn = bn * 128 + wn * 64 + tn * 16 + l15;
                float v = acc[tm][tn][r];
                if (MODE == 0) {
                    int b = gm >> 11, s = gm & 2047;
                    if (gn < 1024) {
                        int h = gn >> 6, d = gn & 63;
                        Qo[(((long)(b * H_ + h) * S_ + s) << 6) + d] = f2bf(v * Cq);
                    } else if (gn < 2048) {
                        int g = gn - 1024; int h = g >> 6, d = g & 63;
                        Ko[(((long)(b * H_ + h) * S_ + s) << 6) + d] = f2bf(v);
                    } else {
                        int g = gn - 2048; int h = g >> 6, d = g & 63;
                        union { _Float16 h; unsigned short u; } cv;
                        cv.h = (_Float16)v;                       // V^T stored FP16
                        Vt[((long)(b * H_ + h) * DH_ + d) * S_ + s] = cv.u;
                    }
                } else {
                    Cout[(long)gm * 1024 + gn] = v;
                }
            }
}

// ---------------- flash attention: 64 q-rows/wave, 2-wave blocks ----------------
// grid (S/128, B*H), 128 threads = 2 waves, each wave owns 64 query rows
// (4 strips of 16). Rationale: the kernel is LDS-bytes bound - every wave
// must read the full 8KB K-tile + 8KB V-tile per iteration regardless of
// MFMA shape. 64 rows/wave amortizes those 16KB over 2x the MFMA vs 32
// rows/wave, and 2 blocks/CU keeps two independent barrier domains so one
// block's vmcnt drain overlaps the other's compute.
// S^T trick: mfma(K_frag, Q_frag) gives the transposed score tile
// (row=key=quad*4+r, col=qrow=l15) -> each lane's 4 acc regs are 4
// consecutive keys -> P packs via v_cvt_pkrtz into b64 LDS stores.
// PV runs fp16 mfma with V^T staged fp16. Q pre-scaled by 0.125*log2e.
// Softmax max-free: fractal weights sum to 1 => |w*s| < ~0.1.
__global__ __launch_bounds__(128, 1)
void attn_kernel(const unsigned short* __restrict__ Q, const unsigned short* __restrict__ Kb,
                 const unsigned short* __restrict__ Vt, const float* __restrict__ fw,
                 unsigned short* __restrict__ O)
{
    __shared__ __align__(16) unsigned short Ks[2][64 * 64];
    __shared__ __align__(16) unsigned short Vs[2][64 * 64];
    __shared__ __align__(16) unsigned short P[2][64 * 72];   // fp16 bits, row=qrow, col=key

    const int tid  = threadIdx.x;
    const int lane = tid & 63, wid = tid >> 6;    // wid in {0,1}
    const int quad = lane >> 4, l15 = lane & 15;
    const int bh = blockIdx.y;
    const int qt = blockIdx.x;

    const unsigned short* Kg = Kb + (long)bh * S_ * DH_;
    const unsigned short* Vg = Vt + (long)bh * (long)DH_ * S_;

    bf16x8 qf[4][2];
#pragma unroll
    for (int s = 0; s < 4; s++) {
        const unsigned short* Qp = Q + ((long)bh * S_ + qt * 128 + wid * 64 + s * 16 + l15) * DH_ + quad * 8;
        qf[s][0] = *(const bf16x8*)(Qp);
        qf[s][1] = *(const bf16x8*)(Qp + 32);
    }

    // stage tile kt: 512 16B-chunks each for K and V, 2 waves x 4 issues
    auto issue = [&](int buf, int kt) {
#pragma unroll
        for (int i = 0; i < 4; i++) {
            int base = i * 128 + wid * 64;        // wave-uniform chunk base
            int slot = base + lane;
            int row = slot >> 3, cp = slot & 7;
            int c = cp ^ (row & 7);
            g2l16(Kg + ((long)(kt * 64 + row) * 64 + c * 8), &Ks[buf][base * 8]);
        }
#pragma unroll
        for (int i = 0; i < 4; i++) {
            int base = i * 128 + wid * 64;
            int slot = base + lane;
            int row = slot >> 3, cp = slot & 7;
            int c = cp ^ (row & 7);
            g2l16(Vg + ((long)row * S_ + kt * 64 + c * 8), &Vs[buf][base * 8]);
        }
    };

    f32x4 oacc[4][4] = {};
    float l_r[4] = {0.f, 0.f, 0.f, 0.f};

    issue(0, 0);
    __syncthreads();

    for (int kt = 0; kt < S_ / 64; kt++) {
        const int cur = kt & 1;
        if (kt + 1 < S_ / 64) issue(1 - cur, kt + 1);

        // raw per-key fractal weights (score scale pre-folded into Q)
        f32x4 wvc[4];
#pragma unroll
        for (int t = 0; t < 4; t++) {
            float4 w = *(const float4*)(fw + kt * 64 + t * 16 + quad * 4);
            wvc[t][0] = w.x; wvc[t][1] = w.y; wvc[t][2] = w.z; wvc[t][3] = w.w;
        }

        const unsigned short* Kc = &Ks[cur][0];
        const unsigned short* Vc = &Vs[cur][0];

        // ---- K fragments: read ONCE, feed all 4 q-strips ----
        bf16x8 kf[4][2];
#pragma unroll
        for (int t = 0; t < 4; t++) {
            int row = t * 16 + l15;
            kf[t][0] = *(const bf16x8*)(Kc + (row * 8 + (quad       ^ (l15 & 7))) * 8);
            kf[t][1] = *(const bf16x8*)(Kc + (row * 8 + ((4 + quad) ^ (l15 & 7))) * 8);
        }

        // ---- per strip: S^T = mfma(K,Q); p = 2^(s*w); packed fp16 P write ----
        unsigned short* pb = &P[wid][0];
#pragma unroll
        for (int s = 0; s < 4; s++) {
            f32x4 sacc[4] = {};
#pragma unroll
            for (int t = 0; t < 4; t++) {
                sacc[t] = __builtin_amdgcn_mfma_f32_16x16x32_bf16(kf[t][0], qf[s][0], sacc[t], 0, 0, 0);
                sacc[t] = __builtin_amdgcn_mfma_f32_16x16x32_bf16(kf[t][1], qf[s][1], sacc[t], 0, 0, 0);
            }
#pragma unroll
            for (int t = 0; t < 4; t++) {
                float p0 = __builtin_amdgcn_exp2f(sacc[t][0] * wvc[t][0]);
                float p1 = __builtin_amdgcn_exp2f(sacc[t][1] * wvc[t][1]);
                float p2 = __builtin_amdgcn_exp2f(sacc[t][2] * wvc[t][2]);
                float p3 = __builtin_amdgcn_exp2f(sacc[t][3] * wvc[t][3]);
                l_r[s] += (p0 + p1) + (p2 + p3);
                union { fp16x2 h; unsigned int u; } a, b;
                a.h = __builtin_amdgcn_cvt_pkrtz(p0, p1);
                b.h = __builtin_amdgcn_cvt_pkrtz(p2, p3);
                *(uint2*)(pb + (s * 16 + l15) * 72 + t * 16 + quad * 4) = make_uint2(a.u, b.u);
            }
        }

        // ---- O += P V (fp16 mfma); V fragments read once, feed all 4 strips ----
#pragma unroll
        for (int ks = 0; ks < 2; ks++) {
            f16x8 pf[4];
#pragma unroll
            for (int s = 0; s < 4; s++)
                pf[s] = *(const f16x8*)(pb + (s * 16 + l15) * 72 + ks * 32 + quad * 8);
#pragma unroll
            for (int t = 0; t < 4; t++) {
                int row = t * 16 + l15;
                f16x8 vf = *(const f16x8*)(Vc + (row * 8 + ((ks * 4 + quad) ^ (l15 & 7))) * 8);
#pragma unroll
                for (int s = 0; s < 4; s++)
                    oacc[s][t] = __builtin_amdgcn_mfma_f32_16x16x32_f16(pf[s], vf, oacc[s][t], 0, 0, 0);
            }
        }

        __syncthreads();
    }

    // l reduction: sum over quads (keys were split across quad+regs)
#pragma unroll
    for (int s = 0; s < 4; s++) {
        l_r[s] += __shfl_xor(l_r[s], 16);
        l_r[s] += __shfl_xor(l_r[s], 32);
    }

    int b = bh >> 4, h = bh & 15;
#pragma unroll
    for (int s = 0; s < 4; s++)
#pragma unroll
        for (int r = 0; r < 4; r++) {
            float inv = 1.0f / __shfl(l_r[s], quad * 4 + r);   // lane q4r holds qrow q4r's sum
            int srow = qt * 128 + wid * 64 + s * 16 + quad * 4 + r;
#pragma unroll
            for (int t = 0; t < 4; t++)
                O[((long)(b * S_ + srow)) * 1024 + h * DH_ + t * 16 + l15] = f2bf(oacc[s][t][r] * inv);
        }
}

// ---------------- launch ----------------

extern "C" void kernel_launch(void* const* d_in, const int* in_sizes, int n_in,
                              void* d_out, int out_size, void* d_ws, size_t ws_size,
                              hipStream_t stream)
{
    const float* x  = (const float*)d_in[0];
    const float* Wq = (const float*)d_in[1];
    const float* Wk = (const float*)d_in[2];
    const float* Wv = (const float*)d_in[3];
    const float* Wo = (const float*)d_in[4];
    const float* fw = (const float*)d_in[5];
    float* out = (float*)d_out;

    char* ws = (char*)d_ws;
    unsigned short* xb    = (unsigned short*)(ws);               // 8 MB   [B*S, D] bf16
    unsigned short* WqkvT = (unsigned short*)(ws + 8388608);     // 6 MB   [3072,1024] bf16
    unsigned short* WoT   = (unsigned short*)(ws + 14680064);    // 2 MB   [1024,1024] bf16
    unsigned short* Qb    = (unsigned short*)(ws + 16777216);    // 8 MB   [B,H,S,64] bf16 (pre-scaled)
    unsigned short* Kb    = (unsigned short*)(ws + 25165824);    // 8 MB   [B,H,S,64] bf16
    unsigned short* Vt    = (unsigned short*)(ws + 33554432);    // 8 MB   [B,H,64,S] fp16
    unsigned short* Ob    = xb;                                  // alias: xb dead after gemm1

    convert_x<<<dim3((B_ * S_ * D_) / 4 / 256), dim3(256), 0, stream>>>(x, xb, B_ * S_ * D_);
    transpose_w<<<dim3(32, 32, 4), dim3(32, 8), 0, stream>>>(
        Wq, Wk, Wv, Wo,
        WqkvT, WqkvT + 1024 * 1024, WqkvT + 2 * 1024 * 1024, WoT);
    gemm128<0><<<dim3(24, 32), dim3(256), 0, stream>>>(xb, WqkvT, Qb, Kb, Vt, (float*)nullptr);
    attn_kernel<<<dim3(S_ / 128, B_ * H_), dim3(128), 0, stream>>>(Qb, Kb, Vt, fw, Ob);
    gemm128<1><<<dim3(8, 32), dim3(256), 0, stream>>>(Ob, WoT,
        (unsigned short*)nullptr, (unsigned short*)nullptr, (unsigned short*)nullptr, out);
}

// Round 9
// 212.529 us; speedup vs baseline: 1.0246x; 1.0246x over previous
//
#include <hip/hip_runtime.h>
#include <hip/hip_bf16.h>
#include <stdint.h>

#define B_  2
#define S_  2048
#define D_  1024
#define H_  16
#define DH_ 64

typedef __attribute__((ext_vector_type(8))) __bf16    bf16x8;
typedef __attribute__((ext_vector_type(8))) _Float16  f16x8;
typedef __attribute__((ext_vector_type(4))) _Float16  f16x4;
typedef __attribute__((ext_vector_type(2))) __fp16    fp16x2;   // cvt_pkrtz return type
typedef __attribute__((ext_vector_type(4))) float     f32x4;

__device__ inline unsigned short f2bf(float f) {
    union { float f; uint32_t u; } v; v.f = f;
    uint32_t r = (v.u + 0x7fffu + ((v.u >> 16) & 1u)) >> 16;
    return (unsigned short)r;
}

// async global->LDS, 16B per lane. LDS dest = wave-uniform base + lane*16.
__device__ __forceinline__ void g2l16(const unsigned short* g, unsigned short* l) {
    __builtin_amdgcn_global_load_lds(
        (const __attribute__((address_space(1))) unsigned int*)g,
        (__attribute__((address_space(3))) unsigned int*)l,
        16, 0, 0);
}

// ---------------- conversion kernels ----------------

__global__ void convert_x(const float* __restrict__ x, unsigned short* __restrict__ xb, int n) {
    int i = (blockIdx.x * blockDim.x + threadIdx.x) * 4;
    if (i < n) {
        float4 v = *(const float4*)(x + i);
        ushort4 o;
        o.x = f2bf(v.x); o.y = f2bf(v.y); o.z = f2bf(v.z); o.w = f2bf(v.w);
        *(ushort4*)(xb + i) = o;
    }
}

// transpose+convert 1024x1024 fp32 [K][N] -> bf16 [N][K]; z selects matrix
__global__ void transpose_w(const float* __restrict__ s0, const float* __restrict__ s1,
                            const float* __restrict__ s2, const float* __restrict__ s3,
                            unsigned short* __restrict__ d0, unsigned short* __restrict__ d1,
                            unsigned short* __restrict__ d2, unsigned short* __restrict__ d3) {
    __shared__ float tile[32][33];
    const float* src; unsigned short* dst;
    switch (blockIdx.z) {
        case 0: src = s0; dst = d0; break;
        case 1: src = s1; dst = d1; break;
        case 2: src = s2; dst = d2; break;
        default: src = s3; dst = d3; break;
    }
    int n0 = blockIdx.x * 32, k0 = blockIdx.y * 32;
    int tx = threadIdx.x, ty = threadIdx.y;   // (32, 8)
    for (int j = 0; j < 32; j += 8)
        tile[ty + j][tx] = src[(long)(k0 + ty + j) * 1024 + n0 + tx];
    __syncthreads();
    for (int j = 0; j < 32; j += 8)
        dst[(long)(n0 + ty + j) * 1024 + k0 + tx] = f2bf(tile[tx][ty + j]);
}

// ---------------- 128x128 MFMA GEMM, global_load_lds staging ----------------
// MODE 0: scatter epilogue -> Q[B,H,S,64] bf16 (PRE-SCALED by 0.125*log2e),
//         K[B,H,S,64] bf16, Vt[B,H,64,S] FP16
// MODE 1: C fp32 [M,1024] row-major
template<int MODE>
__global__ __launch_bounds__(256, 2)
void gemm128(const unsigned short* __restrict__ A, const unsigned short* __restrict__ Bt,
             unsigned short* __restrict__ Qo, unsigned short* __restrict__ Ko,
             unsigned short* __restrict__ Vt, float* __restrict__ Cout)
{
    __shared__ __align__(16) unsigned short As[128 * 64];
    __shared__ __align__(16) unsigned short Bs[128 * 64];
    const int tid  = threadIdx.x;
    const int lane = tid & 63, wid = tid >> 6;
    const int quad = lane >> 4, l15 = lane & 15;
    const int wm = wid >> 1, wn = wid & 1;
    const int bm = blockIdx.y, bn = blockIdx.x;
    const int K = 1024;
    f32x4 acc[4][4] = {};
    const long Abase = (long)bm * 128 * K;
    const long Bbase = (long)bn * 128 * K;

    for (int k0 = 0; k0 < K; k0 += 64) {
        __syncthreads();
#pragma unroll
        for (int i = 0; i < 4; i++) {
            int slot = i * 256 + wid * 64 + lane;
            int row = slot >> 3, cp = slot & 7;
            int c = cp ^ (row & 7);
            g2l16(A + Abase + (long)row * K + k0 + c * 8, &As[(i * 256 + wid * 64) * 8]);
        }
#pragma unroll
        for (int i = 0; i < 4; i++) {
            int slot = i * 256 + wid * 64 + lane;
            int row = slot >> 3, cp = slot & 7;
            int c = cp ^ (row & 7);
            g2l16(Bt + Bbase + (long)row * K + k0 + c * 8, &Bs[(i * 256 + wid * 64) * 8]);
        }
        __syncthreads();
#pragma unroll
        for (int ks = 0; ks < 2; ks++) {
            bf16x8 af[4], bfr[4];
#pragma unroll
            for (int t = 0; t < 4; t++) {
                int ra = wm * 64 + t * 16 + l15;
                af[t]  = *(const bf16x8*)(As + ra * 64 + (((ks * 4 + quad) ^ (l15 & 7))) * 8);
                int rb = wn * 64 + t * 16 + l15;
                bfr[t] = *(const bf16x8*)(Bs + rb * 64 + (((ks * 4 + quad) ^ (l15 & 7))) * 8);
            }
#pragma unroll
            for (int tm = 0; tm < 4; tm++)
#pragma unroll
                for (int tn = 0; tn < 4; tn++)
                    acc[tm][tn] = __builtin_amdgcn_mfma_f32_16x16x32_bf16(af[tm], bfr[tn], acc[tm][tn], 0, 0, 0);
        }
    }

    const float Cq = 0.125f * 1.44269504f;   // score scale * log2(e), folded into Q
    for (int tm = 0; tm < 4; tm++)
        for (int tn = 0; tn < 4; tn++)
            for (int r = 0; r < 4; r++) {
                int gm = bm * 128 + wm * 64 + tm * 16 + quad * 4 + r;
                int gn = bn * 128 + wn * 64 + tn * 16 + l15;
                float v = acc[tm][tn][r];
                if (MODE == 0) {
                    int b = gm >> 11, s = gm & 2047;
                    if (gn < 1024) {
                        int h = gn >> 6, d = gn & 63;
                        Qo[(((long)(b * H_ + h) * S_ + s) << 6) + d] = f2bf(v * Cq);
                    } else if (gn < 2048) {
                        int g = gn - 1024; int h = g >> 6, d = g & 63;
                        Ko[(((long)(b * H_ + h) * S_ + s) << 6) + d] = f2bf(v);
                    } else {
                        int g = gn - 2048; int h = g >> 6, d = g & 63;
                        union { _Float16 h; unsigned short u; } cv;
                        cv.h = (_Float16)v;                       // V^T stored FP16
                        Vt[((long)(b * H_ + h) * DH_ + d) * S_ + s] = cv.u;
                    }
                } else {
                    Cout[(long)gm * 1024 + gn] = v;
                }
            }
}

// ---------------- flash attention: register-resident P (no P LDS) ----------------
// grid (S/128, B*H), 256 threads = 4 waves (R6 skeleton: 32 q-rows/wave,
// 8 waves/CU - R7 proved 4 waves/CU is latency-exposed).
// S^T = mfma(K_frag, Q_frag) -> acc[key=quad*4+r][q=l15]. KEY IDENTITY:
// the mfma_f32_16x16x16_f16 A-fragment layout is [m=l15][k=quad*4+j], which
// is EXACTLY the S^T accumulator transposed - so exp(sacc)*w packed via
// cvt_pkrtz IS the PV left operand. P never touches LDS (R6 spent 8 b64
// writes + 4 b128 reads + lgkmcnt serialization per wave-iter on it).
// PV: K=16 f16 mfma, V^T fragments are shared b64 reads from the swizzled
// V tile (2-way conflict = free). Q pre-scaled by 0.125*log2e; softmax
// max-free (fractal weights sum to 1 => |w*s| < ~0.1).
__global__ __launch_bounds__(256, 2)
void attn_kernel(const unsigned short* __restrict__ Q, const unsigned short* __restrict__ Kb,
                 const unsigned short* __restrict__ Vt, const float* __restrict__ fw,
                 unsigned short* __restrict__ O)
{
    __shared__ __align__(16) unsigned short Ks[2][64 * 64];
    __shared__ __align__(16) unsigned short Vs[2][64 * 64];

    const int tid  = threadIdx.x;
    const int lane = tid & 63, wid = tid >> 6;
    const int quad = lane >> 4, l15 = lane & 15;
    const int bh = blockIdx.y;
    const int qt = blockIdx.x;

    const unsigned short* Kg = Kb + (long)bh * S_ * DH_;
    const unsigned short* Vg = Vt + (long)bh * (long)DH_ * S_;

    bf16x8 qf[2][2];
#pragma unroll
    for (int s = 0; s < 2; s++) {
        const unsigned short* Qp = Q + ((long)bh * S_ + qt * 128 + wid * 32 + s * 16 + l15) * DH_ + quad * 8;
        qf[s][0] = *(const bf16x8*)(Qp);
        qf[s][1] = *(const bf16x8*)(Qp + 32);
    }

    auto issue = [&](int buf, int kt) {
#pragma unroll
        for (int i = 0; i < 2; i++) {
            int slot = wid * 128 + i * 64 + lane;
            int row = slot >> 3, cp = slot & 7;
            int c = cp ^ (row & 7);
            g2l16(Kg + ((long)(kt * 64 + row) * 64 + c * 8), &Ks[buf][(wid * 128 + i * 64) * 8]);
        }
#pragma unroll
        for (int i = 0; i < 2; i++) {
            int slot = wid * 128 + i * 64 + lane;
            int row = slot >> 3, cp = slot & 7;
            int c = cp ^ (row & 7);
            g2l16(Vg + ((long)row * S_ + kt * 64 + c * 8), &Vs[buf][(wid * 128 + i * 64) * 8]);
        }
    };

    f32x4 oacc[2][4] = {};
    float l_r[2] = {0.f, 0.f};

    issue(0, 0);
    __syncthreads();

    for (int kt = 0; kt < S_ / 64; kt++) {
        const int cur = kt & 1;
        if (kt + 1 < S_ / 64) issue(1 - cur, kt + 1);

        // raw per-key fractal weights (score scale pre-folded into Q);
        // this lane's 4 consecutive keys per 16-key chunk kc
        f32x4 wvc[4];
#pragma unroll
        for (int kc = 0; kc < 4; kc++) {
            float4 w = *(const float4*)(fw + kt * 64 + kc * 16 + quad * 4);
            wvc[kc][0] = w.x; wvc[kc][1] = w.y; wvc[kc][2] = w.z; wvc[kc][3] = w.w;
        }

        const unsigned short* Kc = &Ks[cur][0];
        const unsigned short* Vc = &Vs[cur][0];

        // ---- S^T tiles: mfma(K_frag, Q_frag) -> [key=quad*4+r][q=l15] ----
        f32x4 sacc[2][4] = {};
#pragma unroll
        for (int kc = 0; kc < 4; kc++) {
            int row = kc * 16 + l15;
            bf16x8 k0 = *(const bf16x8*)(Kc + (row * 8 + (quad       ^ (l15 & 7))) * 8);
            bf16x8 k1 = *(const bf16x8*)(Kc + (row * 8 + ((4 + quad) ^ (l15 & 7))) * 8);
#pragma unroll
            for (int s = 0; s < 2; s++) {
                sacc[s][kc] = __builtin_amdgcn_mfma_f32_16x16x32_bf16(k0, qf[s][0], sacc[s][kc], 0, 0, 0);
                sacc[s][kc] = __builtin_amdgcn_mfma_f32_16x16x32_bf16(k1, qf[s][1], sacc[s][kc], 0, 0, 0);
            }
        }

        // ---- p = 2^(s*w) packed straight into PV A-fragments (registers!) ----
        f16x4 pk[2][4];
#pragma unroll
        for (int s = 0; s < 2; s++)
#pragma unroll
            for (int kc = 0; kc < 4; kc++) {
                float p0 = __builtin_amdgcn_exp2f(sacc[s][kc][0] * wvc[kc][0]);
                float p1 = __builtin_amdgcn_exp2f(sacc[s][kc][1] * wvc[kc][1]);
                float p2 = __builtin_amdgcn_exp2f(sacc[s][kc][2] * wvc[kc][2]);
                float p3 = __builtin_amdgcn_exp2f(sacc[s][kc][3] * wvc[kc][3]);
                l_r[s] += (p0 + p1) + (p2 + p3);
                union { fp16x2 h; unsigned int u; } a, b;
                a.h = __builtin_amdgcn_cvt_pkrtz(p0, p1);
                b.h = __builtin_amdgcn_cvt_pkrtz(p2, p3);
                union { uint2 u; f16x4 v; } pku;
                pku.u = make_uint2(a.u, b.u);
                pk[s][kc] = pku.v;
            }

        // ---- O += P V via K=16 f16 mfma; V^T b64 fragments shared by strips ----
#pragma unroll
        for (int kc = 0; kc < 4; kc++)
#pragma unroll
            for (int dt = 0; dt < 4; dt++) {
                int row = dt * 16 + l15;
                int pos = (kc * 2 + (quad >> 1)) ^ (l15 & 7);   // swizzled 16B chunk
                f16x4 vf = *(const f16x4*)(Vc + row * 64 + pos * 8 + (quad & 1) * 4);
                oacc[0][dt] = __builtin_amdgcn_mfma_f32_16x16x16f16(pk[0][kc], vf, oacc[0][dt], 0, 0, 0);
                oacc[1][dt] = __builtin_amdgcn_mfma_f32_16x16x16f16(pk[1][kc], vf, oacc[1][dt], 0, 0, 0);
            }

        __syncthreads();
    }

    // l reduction: sum over quads (keys were split across quad+regs)
#pragma unroll
    for (int s = 0; s < 2; s++) {
        l_r[s] += __shfl_xor(l_r[s], 16);
        l_r[s] += __shfl_xor(l_r[s], 32);
    }

    int b = bh >> 4, h = bh & 15;
#pragma unroll
    for (int s = 0; s < 2; s++)
#pragma unroll
        for (int r = 0; r < 4; r++) {
            float inv = 1.0f / __shfl(l_r[s], quad * 4 + r);   // lane q4r holds qrow q4r's sum
            int srow = qt * 128 + wid * 32 + s * 16 + quad * 4 + r;
#pragma unroll
            for (int dt = 0; dt < 4; dt++)
                O[((long)(b * S_ + srow)) * 1024 + h * DH_ + dt * 16 + l15] = f2bf(oacc[s][dt][r] * inv);
        }
}

// ---------------- launch ----------------

extern "C" void kernel_launch(void* const* d_in, const int* in_sizes, int n_in,
                              void* d_out, int out_size, void* d_ws, size_t ws_size,
                              hipStream_t stream)
{
    const float* x  = (const float*)d_in[0];
    const float* Wq = (const float*)d_in[1];
    const float* Wk = (const float*)d_in[2];
    const float* Wv = (const float*)d_in[3];
    const float* Wo = (const float*)d_in[4];
    const float* fw = (const float*)d_in[5];
    float* out = (float*)d_out;

    char* ws = (char*)d_ws;
    unsigned short* xb    = (unsigned short*)(ws);               // 8 MB   [B*S, D] bf16
    unsigned short* WqkvT = (unsigned short*)(ws + 8388608);     // 6 MB   [3072,1024] bf16
    unsigned short* WoT   = (unsigned short*)(ws + 14680064);    // 2 MB   [1024,1024] bf16
    unsigned short* Qb    = (unsigned short*)(ws + 16777216);    // 8 MB   [B,H,S,64] bf16 (pre-scaled)
    unsigned short* Kb    = (unsigned short*)(ws + 25165824);    // 8 MB   [B,H,S,64] bf16
    unsigned short* Vt    = (unsigned short*)(ws + 33554432);    // 8 MB   [B,H,64,S] fp16
    unsigned short* Ob    = xb;                                  // alias: xb dead after gemm1

    convert_x<<<dim3((B_ * S_ * D_) / 4 / 256), dim3(256), 0, stream>>>(x, xb, B_ * S_ * D_);
    transpose_w<<<dim3(32, 32, 4), dim3(32, 8), 0, stream>>>(
        Wq, Wk, Wv, Wo,
        WqkvT, WqkvT + 1024 * 1024, WqkvT + 2 * 1024 * 1024, WoT);
    gemm128<0><<<dim3(24, 32), dim3(256), 0, stream>>>(xb, WqkvT, Qb, Kb, Vt, (float*)nullptr);
    attn_kernel<<<dim3(S_ / 128, B_ * H_), dim3(256), 0, stream>>>(Qb, Kb, Vt, fw, Ob);
    gemm128<1><<<dim3(8, 32), dim3(256), 0, stream>>>(Ob, WoT,
        (unsigned short*)nullptr, (unsigned short*)nullptr, (unsigned short*)nullptr, out);
}

// Round 10
// 200.546 us; speedup vs baseline: 1.0858x; 1.0597x over previous
//
#include <hip/hip_runtime.h>
#include <hip/hip_bf16.h>
#include <stdint.h>

#define B_  2
#define S_  2048
#define D_  1024
#define H_  16
#define DH_ 64

typedef __attribute__((ext_vector_type(8))) __bf16    bf16x8;
typedef __attribute__((ext_vector_type(8))) _Float16  f16x8;
typedef __attribute__((ext_vector_type(4))) _Float16  f16x4;
typedef __attribute__((ext_vector_type(2))) __fp16    fp16x2;   // cvt_pkrtz return type
typedef __attribute__((ext_vector_type(4))) float     f32x4;

__device__ inline unsigned short f2bf(float f) {
    union { float f; uint32_t u; } v; v.f = f;
    uint32_t r = (v.u + 0x7fffu + ((v.u >> 16) & 1u)) >> 16;
    return (unsigned short)r;
}

// async global->LDS, 16B per lane. LDS dest = wave-uniform base + lane*16.
__device__ __forceinline__ void g2l16(const unsigned short* g, unsigned short* l) {
    __builtin_amdgcn_global_load_lds(
        (const __attribute__((address_space(1))) unsigned int*)g,
        (__attribute__((address_space(3))) unsigned int*)l,
        16, 0, 0);
}

// ---------------- conversion kernels ----------------

__global__ void convert_x(const float* __restrict__ x, unsigned short* __restrict__ xb, int n) {
    int i = (blockIdx.x * blockDim.x + threadIdx.x) * 4;
    if (i < n) {
        float4 v = *(const float4*)(x + i);
        ushort4 o;
        o.x = f2bf(v.x); o.y = f2bf(v.y); o.z = f2bf(v.z); o.w = f2bf(v.w);
        *(ushort4*)(xb + i) = o;
    }
}

// transpose+convert 1024x1024 fp32 [K][N] -> bf16 [N][K]; z selects matrix
__global__ void transpose_w(const float* __restrict__ s0, const float* __restrict__ s1,
                            const float* __restrict__ s2, const float* __restrict__ s3,
                            unsigned short* __restrict__ d0, unsigned short* __restrict__ d1,
                            unsigned short* __restrict__ d2, unsigned short* __restrict__ d3) {
    __shared__ float tile[32][33];
    const float* src; unsigned short* dst;
    switch (blockIdx.z) {
        case 0: src = s0; dst = d0; break;
        case 1: src = s1; dst = d1; break;
        case 2: src = s2; dst = d2; break;
        default: src = s3; dst = d3; break;
    }
    int n0 = blockIdx.x * 32, k0 = blockIdx.y * 32;
    int tx = threadIdx.x, ty = threadIdx.y;   // (32, 8)
    for (int j = 0; j < 32; j += 8)
        tile[ty + j][tx] = src[(long)(k0 + ty + j) * 1024 + n0 + tx];
    __syncthreads();
    for (int j = 0; j < 32; j += 8)
        dst[(long)(n0 + ty + j) * 1024 + k0 + tx] = f2bf(tile[tx][ty + j]);
}

// ---------------- 128x128 MFMA GEMM, global_load_lds staging ----------------
// MODE 0: scatter epilogue -> Q[B,H,S,64] bf16 (PRE-SCALED by 0.125*log2e),
//         K[B,H,S,64] bf16 (PRE-SCALED by fw[s] - fractal weight folded in),
//         Vt[B,H,64,S] FP16
// MODE 1: C fp32 [M,1024] row-major
template<int MODE>
__global__ __launch_bounds__(256, 2)
void gemm128(const unsigned short* __restrict__ A, const unsigned short* __restrict__ Bt,
             unsigned short* __restrict__ Qo, unsigned short* __restrict__ Ko,
             unsigned short* __restrict__ Vt, float* __restrict__ Cout,
             const float* __restrict__ fw)
{
    __shared__ __align__(16) unsigned short As[128 * 64];
    __shared__ __align__(16) unsigned short Bs[128 * 64];
    const int tid  = threadIdx.x;
    const int lane = tid & 63, wid = tid >> 6;
    const int quad = lane >> 4, l15 = lane & 15;
    const int wm = wid >> 1, wn = wid & 1;
    const int bm = blockIdx.y, bn = blockIdx.x;
    const int K = 1024;
    f32x4 acc[4][4] = {};
    const long Abase = (long)bm * 128 * K;
    const long Bbase = (long)bn * 128 * K;

    for (int k0 = 0; k0 < K; k0 += 64) {
        __syncthreads();
#pragma unroll
        for (int i = 0; i < 4; i++) {
            int slot = i * 256 + wid * 64 + lane;
            int row = slot >> 3, cp = slot & 7;
            int c = cp ^ (row & 7);
            g2l16(A + Abase + (long)row * K + k0 + c * 8, &As[(i * 256 + wid * 64) * 8]);
        }
#pragma unroll
        for (int i = 0; i < 4; i++) {
            int slot = i * 256 + wid * 64 + lane;
            int row = slot >> 3, cp = slot & 7;
            int c = cp ^ (row & 7);
            g2l16(Bt + Bbase + (long)row * K + k0 + c * 8, &Bs[(i * 256 + wid * 64) * 8]);
        }
        __syncthreads();
#pragma unroll
        for (int ks = 0; ks < 2; ks++) {
            bf16x8 af[4], bfr[4];
#pragma unroll
            for (int t = 0; t < 4; t++) {
                int ra = wm * 64 + t * 16 + l15;
                af[t]  = *(const bf16x8*)(As + ra * 64 + (((ks * 4 + quad) ^ (l15 & 7))) * 8);
                int rb = wn * 64 + t * 16 + l15;
                bfr[t] = *(const bf16x8*)(Bs + rb * 64 + (((ks * 4 + quad) ^ (l15 & 7))) * 8);
            }
#pragma unroll
            for (int tm = 0; tm < 4; tm++)
#pragma unroll
                for (int tn = 0; tn < 4; tn++)
                    acc[tm][tn] = __builtin_amdgcn_mfma_f32_16x16x32_bf16(af[tm], bfr[tn], acc[tm][tn], 0, 0, 0);
        }
    }

    const float Cq = 0.125f * 1.44269504f;   // score scale * log2(e), folded into Q
    for (int tm = 0; tm < 4; tm++)
        for (int tn = 0; tn < 4; tn++)
            for (int r = 0; r < 4; r++) {
                int gm = bm * 128 + wm * 64 + tm * 16 + quad * 4 + r;
                int gn = bn * 128 + wn * 64 + tn * 16 + l15;
                float v = acc[tm][tn][r];
                if (MODE == 0) {
                    int b = gm >> 11, s = gm & 2047;
                    if (gn < 1024) {
                        int h = gn >> 6, d = gn & 63;
                        Qo[(((long)(b * H_ + h) * S_ + s) << 6) + d] = f2bf(v * Cq);
                    } else if (gn < 2048) {
                        int g = gn - 1024; int h = g >> 6, d = g & 63;
                        Ko[(((long)(b * H_ + h) * S_ + s) << 6) + d] = f2bf(v * fw[s]);
                    } else {
                        int g = gn - 2048; int h = g >> 6, d = g & 63;
                        union { _Float16 h; unsigned short u; } cv;
                        cv.h = (_Float16)v;                       // V^T stored FP16
                        Vt[((long)(b * H_ + h) * DH_ + d) * S_ + s] = cv.u;
                    }
                } else {
                    Cout[(long)gm * 1024 + gn] = v;
                }
            }
}

// ---------------- flash attention: register P + 4 barrier domains/CU ----------------
// grid (S/64, B*H), 128 threads = 2 waves, 32 q-rows/wave (64 q-rows/block).
// R8 post-mortem: MfmaUtil 27 + VALUBusy 33 + LDS ~37 ~= 97% with NOTHING
// saturated = phase lockstep (all waves in a barrier domain do LDS reads,
// then exp, then MFMA together; only 2 domains/CU). This kernel keeps the
// SAME 8 waves/CU but as 4 blocks x 2 waves -> 4 desynchronized barrier
// domains whose phases interleave across pipes.
// Register-P (R8): S^T = mfma(K_frag, Q_frag) -> acc[key=quad*4+r][q=l15];
// exp2 of it packed via cvt_pkrtz IS the K=16 f16 PV A-fragment; P never
// touches LDS. fw is folded into K at gemm0 (K rows pre-scaled by fw[s]),
// Q pre-scaled by 0.125*log2e -> softmax here is literally exp2(sacc).
// Max-free softmax: fractal weights sum to 1 => |arg| < ~0.1.
__global__ __launch_bounds__(128, 2)
void attn_kernel(const unsigned short* __restrict__ Q, const unsigned short* __restrict__ Kb,
                 const unsigned short* __restrict__ Vt,
                 unsigned short* __restrict__ O)
{
    __shared__ __align__(16) unsigned short Ks[2][64 * 64];
    __shared__ __align__(16) unsigned short Vs[2][64 * 64];

    const int tid  = threadIdx.x;
    const int lane = tid & 63, wid = tid >> 6;    // wid in {0,1}
    const int quad = lane >> 4, l15 = lane & 15;
    const int bh = blockIdx.y;
    const int qt = blockIdx.x;

    const unsigned short* Kg = Kb + (long)bh * S_ * DH_;
    const unsigned short* Vg = Vt + (long)bh * (long)DH_ * S_;

    bf16x8 qf[2][2];
#pragma unroll
    for (int s = 0; s < 2; s++) {
        const unsigned short* Qp = Q + ((long)bh * S_ + qt * 64 + wid * 32 + s * 16 + l15) * DH_ + quad * 8;
        qf[s][0] = *(const bf16x8*)(Qp);
        qf[s][1] = *(const bf16x8*)(Qp + 32);
    }

    // stage tile kt: 512 16B-chunks each for K and V, 2 waves x 4 issues each
    auto issue = [&](int buf, int kt) {
#pragma unroll
        for (int i = 0; i < 4; i++) {
            int base = i * 128 + wid * 64;
            int slot = base + lane;
            int row = slot >> 3, cp = slot & 7;
            int c = cp ^ (row & 7);
            g2l16(Kg + ((long)(kt * 64 + row) * 64 + c * 8), &Ks[buf][base * 8]);
        }
#pragma unroll
        for (int i = 0; i < 4; i++) {
            int base = i * 128 + wid * 64;
            int slot = base + lane;
            int row = slot >> 3, cp = slot & 7;
            int c = cp ^ (row & 7);
            g2l16(Vg + ((long)row * S_ + kt * 64 + c * 8), &Vs[buf][base * 8]);
        }
    };

    f32x4 oacc[2][4] = {};
    float l_r[2] = {0.f, 0.f};

    issue(0, 0);
    __syncthreads();

    for (int kt = 0; kt < S_ / 64; kt++) {
        const int cur = kt & 1;
        if (kt + 1 < S_ / 64) issue(1 - cur, kt + 1);

        const unsigned short* Kc = &Ks[cur][0];
        const unsigned short* Vc = &Vs[cur][0];

        // ---- S^T tiles: mfma(K_frag, Q_frag) -> [key=quad*4+r][q=l15] ----
        f32x4 sacc[2][4] = {};
#pragma unroll
        for (int kc = 0; kc < 4; kc++) {
            int row = kc * 16 + l15;
            bf16x8 k0 = *(const bf16x8*)(Kc + (row * 8 + (quad       ^ (l15 & 7))) * 8);
            bf16x8 k1 = *(const bf16x8*)(Kc + (row * 8 + ((4 + quad) ^ (l15 & 7))) * 8);
#pragma unroll
            for (int s = 0; s < 2; s++) {
                sacc[s][kc] = __builtin_amdgcn_mfma_f32_16x16x32_bf16(k0, qf[s][0], sacc[s][kc], 0, 0, 0);
                sacc[s][kc] = __builtin_amdgcn_mfma_f32_16x16x32_bf16(k1, qf[s][1], sacc[s][kc], 0, 0, 0);
            }
        }

        // ---- p = 2^sacc packed straight into PV A-fragments (registers) ----
        f16x4 pk[2][4];
#pragma unroll
        for (int s = 0; s < 2; s++)
#pragma unroll
            for (int kc = 0; kc < 4; kc++) {
                float p0 = __builtin_amdgcn_exp2f(sacc[s][kc][0]);
                float p1 = __builtin_amdgcn_exp2f(sacc[s][kc][1]);
                float p2 = __builtin_amdgcn_exp2f(sacc[s][kc][2]);
                float p3 = __builtin_amdgcn_exp2f(sacc[s][kc][3]);
                l_r[s] += (p0 + p1) + (p2 + p3);
                union { fp16x2 h; unsigned int u; } a, b;
                a.h = __builtin_amdgcn_cvt_pkrtz(p0, p1);
                b.h = __builtin_amdgcn_cvt_pkrtz(p2, p3);
                union { uint2 u; f16x4 v; } pku;
                pku.u = make_uint2(a.u, b.u);
                pk[s][kc] = pku.v;
            }

        // ---- O += P V via K=16 f16 mfma; V^T b64 fragments shared by strips ----
#pragma unroll
        for (int kc = 0; kc < 4; kc++)
#pragma unroll
            for (int dt = 0; dt < 4; dt++) {
                int row = dt * 16 + l15;
                int pos = (kc * 2 + (quad >> 1)) ^ (l15 & 7);   // swizzled 16B chunk
                f16x4 vf = *(const f16x4*)(Vc + row * 64 + pos * 8 + (quad & 1) * 4);
                oacc[0][dt] = __builtin_amdgcn_mfma_f32_16x16x16f16(pk[0][kc], vf, oacc[0][dt], 0, 0, 0);
                oacc[1][dt] = __builtin_amdgcn_mfma_f32_16x16x16f16(pk[1][kc], vf, oacc[1][dt], 0, 0, 0);
            }

        __syncthreads();
    }

    // l reduction: sum over quads (keys were split across quad+regs)
#pragma unroll
    for (int s = 0; s < 2; s++) {
        l_r[s] += __shfl_xor(l_r[s], 16);
        l_r[s] += __shfl_xor(l_r[s], 32);
    }

    int b = bh >> 4, h = bh & 15;
#pragma unroll
    for (int s = 0; s < 2; s++)
#pragma unroll
        for (int r = 0; r < 4; r++) {
            float inv = 1.0f / __shfl(l_r[s], quad * 4 + r);   // lane q4r holds qrow q4r's sum
            int srow = qt * 64 + wid * 32 + s * 16 + quad * 4 + r;
#pragma unroll
            for (int dt = 0; dt < 4; dt++)
                O[((long)(b * S_ + srow)) * 1024 + h * DH_ + dt * 16 + l15] = f2bf(oacc[s][dt][r] * inv);
        }
}

// ---------------- launch ----------------

extern "C" void kernel_launch(void* const* d_in, const int* in_sizes, int n_in,
                              void* d_out, int out_size, void* d_ws, size_t ws_size,
                              hipStream_t stream)
{
    const float* x  = (const float*)d_in[0];
    const float* Wq = (const float*)d_in[1];
    const float* Wk = (const float*)d_in[2];
    const float* Wv = (const float*)d_in[3];
    const float* Wo = (const float*)d_in[4];
    const float* fw = (const float*)d_in[5];
    float* out = (float*)d_out;

    char* ws = (char*)d_ws;
    unsigned short* xb    = (unsigned short*)(ws);               // 8 MB   [B*S, D] bf16
    unsigned short* WqkvT = (unsigned short*)(ws + 8388608);     // 6 MB   [3072,1024] bf16
    unsigned short* WoT   = (unsigned short*)(ws + 14680064);    // 2 MB   [1024,1024] bf16
    unsigned short* Qb    = (unsigned short*)(ws + 16777216);    // 8 MB   [B,H,S,64] bf16 (pre-scaled Cq)
    unsigned short* Kb    = (unsigned short*)(ws + 25165824);    // 8 MB   [B,H,S,64] bf16 (pre-scaled fw)
    unsigned short* Vt    = (unsigned short*)(ws + 33554432);    // 8 MB   [B,H,64,S] fp16
    unsigned short* Ob    = xb;                                  // alias: xb dead after gemm1

    convert_x<<<dim3((B_ * S_ * D_) / 4 / 256), dim3(256), 0, stream>>>(x, xb, B_ * S_ * D_);
    transpose_w<<<dim3(32, 32, 4), dim3(32, 8), 0, stream>>>(
        Wq, Wk, Wv, Wo,
        WqkvT, WqkvT + 1024 * 1024, WqkvT + 2 * 1024 * 1024, WoT);
    gemm128<0><<<dim3(24, 32), dim3(256), 0, stream>>>(xb, WqkvT, Qb, Kb, Vt, (float*)nullptr, fw);
    attn_kernel<<<dim3(S_ / 64, B_ * H_), dim3(128), 0, stream>>>(Qb, Kb, Vt, Ob);
    gemm128<1><<<dim3(8, 32), dim3(256), 0, stream>>>(Ob, WoT,
        (unsigned short*)nullptr, (unsigned short*)nullptr, (unsigned short*)nullptr, out, (const float*)nullptr);
}